// Round 4
// baseline (293.364 us; speedup 1.0000x reference)
//
#include <hip/hip_runtime.h>

// Problem constants (B=16, C=64, H=W=128, num_heads=4). All tensors fp32.
#define HW     16384    // H*W
#define CPH    16       // channels per head
#define NBH    64       // B * num_heads
#define NS     16       // k slices per (b,h) in gram kernel
#define KSLICE (HW/NS)  // 1024
#define TKT    256      // k columns per LDS tile
#define LS     260      // LDS row stride in floats
#define KPT    4        // k per thread in apply kernel (one float4)

// ws layout (floats) — plain-stored partials, NO zero-init needed:
//  GP  : [64][16][256]  offset 0       per-slice gram partials (c*16+d)
//  SXP : [64][16][16]   offset 262144  per-slice sum x^2
//  SYP : [64][16][16]   offset 278528  per-slice sum y^2
#define WS_GP   0
#define WS_SXP  262144
#define WS_SYP  278528

// Kernel 1: per (bh, slice): partial G[c][d] = sum_k x[c,k]*y[d,k], SX, SY.
// Grid: NBH*NS = 1024 blocks (4/CU), 256 threads. LDS-tiled: stage 16x256 of
// x,y fully coalesced (each element fetched once), 16 k-groups x 16 threads
// compute 4x4 register tiles with strided c/d for conflict-free LDS reads.
__global__ __launch_bounds__(256) void gram_kernel(
    const float* __restrict__ x,
    const float* __restrict__ y,
    float* __restrict__ ws)
{
    __shared__ float xs[16 * LS];
    __shared__ float ys[16 * LS];
    __shared__ float Gs[256];
    __shared__ float sxs[16], sys[16];

    const int blk = blockIdx.x;
    const int bh  = blk >> 4;              // / NS
    const int sl  = blk & (NS - 1);
    const int ks  = sl * KSLICE;
    const int t   = threadIdx.x;

    Gs[t] = 0.f;
    if (t < 16) { sxs[t] = 0.f; sys[t] = 0.f; }

    const int c0 = t & 3;          // strided c base
    const int d0 = (t >> 2) & 3;   // strided d base
    const int g  = t >> 4;         // k-group (16 cols per tile)

    float acc[4][4];
    #pragma unroll
    for (int i = 0; i < 4; ++i)
        #pragma unroll
        for (int j = 0; j < 4; ++j) acc[i][j] = 0.f;
    float sqx[4] = {0.f, 0.f, 0.f, 0.f};
    float sqy[4] = {0.f, 0.f, 0.f, 0.f};

    const float* xb = x + (size_t)bh * CPH * HW + ks;
    const float* yb = y + (size_t)bh * CPH * HW + ks;

    for (int kt = 0; kt < KSLICE; kt += TKT) {
        __syncthreads();   // previous tile consumed (also covers Gs init)
        #pragma unroll
        for (int i = 0; i < 4; ++i) {
            int idx = i * 256 + t;
            int row = idx >> 6;
            int col = (idx & 63) * 4;
            float4 xv = *reinterpret_cast<const float4*>(xb + (size_t)row * HW + kt + col);
            float4 yv = *reinterpret_cast<const float4*>(yb + (size_t)row * HW + kt + col);
            *reinterpret_cast<float4*>(&xs[row * LS + col]) = xv;
            *reinterpret_cast<float4*>(&ys[row * LS + col]) = yv;
        }
        __syncthreads();

        // group g owns columns [g*16, g*16+16) of this tile
        #pragma unroll
        for (int kq = 0; kq < 16; kq += 4) {
            float4 xr[4], yr[4];
            #pragma unroll
            for (int i = 0; i < 4; ++i)
                xr[i] = *reinterpret_cast<const float4*>(&xs[(c0 + 4 * i) * LS + g * 16 + kq]);
            #pragma unroll
            for (int j = 0; j < 4; ++j)
                yr[j] = *reinterpret_cast<const float4*>(&ys[(d0 + 4 * j) * LS + g * 16 + kq]);
            #pragma unroll
            for (int i = 0; i < 4; ++i)
                #pragma unroll
                for (int j = 0; j < 4; ++j) {
                    acc[i][j] = fmaf(xr[i].x, yr[j].x, acc[i][j]);
                    acc[i][j] = fmaf(xr[i].y, yr[j].y, acc[i][j]);
                    acc[i][j] = fmaf(xr[i].z, yr[j].z, acc[i][j]);
                    acc[i][j] = fmaf(xr[i].w, yr[j].w, acc[i][j]);
                }
            if (d0 == 0) {
                #pragma unroll
                for (int i = 0; i < 4; ++i) {
                    sqx[i] = fmaf(xr[i].x, xr[i].x, sqx[i]);
                    sqx[i] = fmaf(xr[i].y, xr[i].y, sqx[i]);
                    sqx[i] = fmaf(xr[i].z, xr[i].z, sqx[i]);
                    sqx[i] = fmaf(xr[i].w, xr[i].w, sqx[i]);
                }
            }
            if (c0 == 0) {
                #pragma unroll
                for (int j = 0; j < 4; ++j) {
                    sqy[j] = fmaf(yr[j].x, yr[j].x, sqy[j]);
                    sqy[j] = fmaf(yr[j].y, yr[j].y, sqy[j]);
                    sqy[j] = fmaf(yr[j].z, yr[j].z, sqy[j]);
                    sqy[j] = fmaf(yr[j].w, yr[j].w, sqy[j]);
                }
            }
        }
    }

    // block-level reduction in LDS, then plain partial stores (no global atomics)
    #pragma unroll
    for (int i = 0; i < 4; ++i)
        #pragma unroll
        for (int j = 0; j < 4; ++j)
            atomicAdd(&Gs[(c0 + 4 * i) * 16 + (d0 + 4 * j)], acc[i][j]);
    if (d0 == 0) {
        #pragma unroll
        for (int i = 0; i < 4; ++i) atomicAdd(&sxs[c0 + 4 * i], sqx[i]);
    }
    if (c0 == 0) {
        #pragma unroll
        for (int j = 0; j < 4; ++j) atomicAdd(&sys[d0 + 4 * j], sqy[j]);
    }
    __syncthreads();
    ws[WS_GP + (bh * NS + sl) * 256 + t] = Gs[t];
    if (t < 16)       ws[WS_SXP + (bh * NS + sl) * 16 + t]        = sxs[t];
    else if (t < 32)  ws[WS_SYP + (bh * NS + sl) * 16 + (t - 16)] = sys[t - 16];
}

// Kernel 2 (fused softmax + apply):
// Phase 1: reduce the 16 per-slice partials, normalize to cosine energy,
//          row-softmax (attn1) + col-softmax (attn2), temperature-scale, LDS.
// Phase 2: out_x[d,k] = sum_c W2[c][d]*x[c,k] + y[d,k]   (channels 0..63)
//          out_y[d,k] = sum_c W1[c][d]*y[c,k] + x[d,k]   (channels 64..127)
// Grid: NBH * (HW/(256*KPT)) = 1024 blocks, 256 threads, one float4 k/thread.
__global__ __launch_bounds__(256) void apply_kernel(
    const float* __restrict__ x,
    const float* __restrict__ y,
    const float* __restrict__ ws,
    const float* __restrict__ t1p,
    const float* __restrict__ t2p,
    float* __restrict__ out)
{
    const int CHUNKS = HW / (256 * KPT);       // 16
    const int blk   = blockIdx.x;
    const int bh    = blk / CHUNKS;
    const int chunk = blk % CHUNKS;
    const int t     = threadIdx.x;
    const int i     = t >> 4;
    const int j     = t & 15;

    __shared__ float Es[256];
    __shared__ float SXs[16], SYs[16];
    __shared__ float W1s[256], W2s[256];

    // ---- Phase 1: weights ----
    {
        float gsum = 0.f;
        const float* gp = ws + WS_GP + bh * NS * 256 + t;
        #pragma unroll
        for (int s = 0; s < NS; ++s) gsum += gp[s * 256];
        if (t < 16) {
            float v = 0.f;
            const float* p = ws + WS_SXP + bh * NS * 16 + t;
            #pragma unroll
            for (int s = 0; s < NS; ++s) v += p[s * 16];
            SXs[t] = v;
        } else if (t < 32) {
            float v = 0.f;
            const float* p = ws + WS_SYP + bh * NS * 16 + (t - 16);
            #pragma unroll
            for (int s = 0; s < NS; ++s) v += p[s * 16];
            SYs[t - 16] = v;
        }
        Es[t] = gsum;
        __syncthreads();

        float nx = fmaxf(sqrtf(SXs[i]), 1e-12f);
        float ny = fmaxf(sqrtf(SYs[j]), 1e-12f);
        float e  = Es[t] / (nx * ny);   // each thread touches only its own slot
        Es[t] = e;
        __syncthreads();

        // row softmax over j (fixed i): attn1[i][j]
        float rm = -1e30f;
        #pragma unroll
        for (int r = 0; r < 16; ++r) rm = fmaxf(rm, Es[i * 16 + r]);
        float rs = 0.f;
        #pragma unroll
        for (int r = 0; r < 16; ++r) rs += expf(Es[i * 16 + r] - rm);
        float a1 = expf(e - rm) / rs;

        // column softmax over rows (fixed j)
        float cm = -1e30f;
        #pragma unroll
        for (int r = 0; r < 16; ++r) cm = fmaxf(cm, Es[r * 16 + j]);
        float cs = 0.f;
        #pragma unroll
        for (int r = 0; r < 16; ++r) cs += expf(Es[r * 16 + j] - cm);
        float v2 = expf(e - cm) / cs;

        const float t1 = t1p[0];
        const float t2 = t2p[0];
        W1s[i * 16 + j] = t1 * a1;   // w1[c=i][d=j]   (y_att: attn1[c][d])
        W2s[j * 16 + i] = t2 * v2;   // w2[c=j][d=i]   (x_att: colsoftmax^T)
        __syncthreads();
    }

    // ---- Phase 2: streamed apply ----
    const int k0 = chunk * (256 * KPT) + t * KPT;
    const int b  = bh >> 2;
    const int h  = bh & 3;

    const float* xbase = x + ((size_t)bh * CPH) * HW + k0;
    const float* ybase = y + ((size_t)bh * CPH) * HW + k0;

    float accx[16][KPT];
    float accy[16][KPT];
    #pragma unroll
    for (int d = 0; d < 16; ++d)
        #pragma unroll
        for (int q = 0; q < KPT; ++q) { accx[d][q] = 0.f; accy[d][q] = 0.f; }

    float4 xq = *reinterpret_cast<const float4*>(xbase);
    float4 yq = *reinterpret_cast<const float4*>(ybase);
    #pragma unroll
    for (int c = 0; c < 16; ++c) {
        float4 xn, yn;
        if (c < 15) {   // prefetch next row while doing this row's FMAs
            xn = *reinterpret_cast<const float4*>(xbase + (size_t)(c + 1) * HW);
            yn = *reinterpret_cast<const float4*>(ybase + (size_t)(c + 1) * HW);
        }
        float xv[KPT] = {xq.x, xq.y, xq.z, xq.w};
        float yv[KPT] = {yq.x, yq.y, yq.z, yq.w};
        #pragma unroll
        for (int d = 0; d < 16; ++d) {
            float w2 = W2s[c * 16 + d];
            float w1 = W1s[c * 16 + d];
            #pragma unroll
            for (int q = 0; q < KPT; ++q) accx[d][q] = fmaf(w2, xv[q], accx[d][q]);
            #pragma unroll
            for (int q = 0; q < KPT; ++q) accy[d][q] = fmaf(w1, yv[q], accy[d][q]);
        }
        // residual fold at d == c:  x_ += y[d],  y_ += x[d]
        #pragma unroll
        for (int q = 0; q < KPT; ++q) accx[c][q] += yv[q];
        #pragma unroll
        for (int q = 0; q < KPT; ++q) accy[c][q] += xv[q];
        xq = xn; yq = yn;
    }

    const size_t obx = ((size_t)b * 128 + h * 16) * HW + k0;   // x_ -> channels 0..63
    const size_t oby = obx + (size_t)64 * HW;                  // y_ -> channels 64..127
    #pragma unroll
    for (int d = 0; d < 16; ++d) {
        float4 px = make_float4(accx[d][0], accx[d][1], accx[d][2], accx[d][3]);
        float4 py = make_float4(accy[d][0], accy[d][1], accy[d][2], accy[d][3]);
        *reinterpret_cast<float4*>(out + obx + (size_t)d * HW) = px;
        *reinterpret_cast<float4*>(out + oby + (size_t)d * HW) = py;
    }
}

extern "C" void kernel_launch(void* const* d_in, const int* in_sizes, int n_in,
                              void* d_out, int out_size, void* d_ws, size_t ws_size,
                              hipStream_t stream) {
    const float* x  = (const float*)d_in[0];
    const float* y  = (const float*)d_in[1];
    const float* t1 = (const float*)d_in[2];
    const float* t2 = (const float*)d_in[3];
    float* ws  = (float*)d_ws;
    float* out = (float*)d_out;

    gram_kernel<<<NBH * NS, 256, 0, stream>>>(x, y, ws);
    apply_kernel<<<NBH * (HW / (256 * KPT)), 256, 0, stream>>>(x, y, ws, t1, t2, out);
}